// Round 7
// baseline (1451.526 us; speedup 1.0000x reference)
//
#include <hip/hip_runtime.h>
#include <hip/hip_bf16.h>
#include <hip/hip_cooperative_groups.h>
#include <stdint.h>

namespace cg = cooperative_groups;

// ---------------- helpers ----------------
__device__ __forceinline__ float bf2f(unsigned short u) {
    unsigned int x = ((unsigned int)u) << 16;
    return __uint_as_float(x);
}
__device__ __forceinline__ unsigned short f2bf(float f) {
    unsigned int x = __float_as_uint(f);
    unsigned int lsb = (x >> 16) & 1u;
    x += 0x7fffu + lsb;           // round-to-nearest-even
    return (unsigned short)(x >> 16);
}
__device__ __forceinline__ float loadF(const void* p, int i, int isbf) {
    return isbf ? bf2f(((const unsigned short*)p)[i]) : ((const float*)p)[i];
}

// ---------------- init: zero bcnt + dtype flags ----------------
__global__ void k_init(const void* x, const void* eidx, int* flags, int* bcnt, int B) {
    int t = threadIdx.x;   // 1024
    for (int b = t; b < B; b += blockDim.x) bcnt[b] = 0;
    if (t < 64) {
        const unsigned short* u = (const unsigned short*)x;
        float a = fabsf(bf2f(u[2 * t]));
        bool ok = (a == 0.0f) || (a > 1e-30f && a < 1e4f);
        unsigned long long mbf = __ballot(ok);
        if (t == 0) flags[0] = (mbf == ~0ULL) ? 1 : 0;
    } else if (t < 128) {
        int l = t - 64;
        const int* ip = (const int*)eidx;
        unsigned long long mi64 = __ballot(ip[2 * l + 1] == 0);
        if (l == 0) flags[1] = (mi64 == ~0ULL) ? 1 : 0;
    }
}

// ---------------- edge binning by dst range ----------------
// Bucket = dst >> rsh (R=128). Packed word = (src << rsh) | (dst & R-1).
__global__ void k_bin(const void* eidx, int E, int rsh, int B, int cap,
                      unsigned int* bins, int* bcnt, const int* flags) {
    extern __shared__ int sh[];            // 2*B ints
    int* hist   = sh;
    int* base_s = sh + B;
    const int i64 = flags[1];
    const int t = threadIdx.x, nt = blockDim.x;
    const long long i0 = (long long)blockIdx.x * E / gridDim.x;
    const long long i1 = (long long)(blockIdx.x + 1) * E / gridDim.x;
    const long long* e64 = (const long long*)eidx;
    const int* e32 = (const int*)eidx;
    const int mask = (1 << rsh) - 1;

    for (int b = t; b < B; b += nt) hist[b] = 0;
    __syncthreads();
    for (long long i = i0 + t; i < i1; i += nt) {
        int d = i64 ? (int)e64[E + i] : e32[E + i];
        atomicAdd(&hist[d >> rsh], 1);
    }
    __syncthreads();
    for (int b = t; b < B; b += nt) {
        int c = hist[b];
        base_s[b] = c ? atomicAdd(&bcnt[b], c) : 0;
        hist[b] = 0;
    }
    __syncthreads();
    for (long long i = i0 + t; i < i1; i += nt) {
        int d, s;
        if (i64) { d = (int)e64[E + i]; s = (int)e64[i]; }
        else     { d = e32[E + i];     s = e32[i]; }
        int b = d >> rsh;
        int pos = base_s[b] + atomicAdd(&hist[b], 1);
        if (pos >= cap) pos = cap - 1;     // paranoia guard
        bins[(size_t)b * cap + pos] = ((unsigned int)s << rsh) | (unsigned int)(d & mask);
    }
}

// ---------------- per-bucket CSR build + degree sort ----------------
__global__ void k_csr(const unsigned int* bins, const int* bcnt, int cap, int rsh,
                      int n, int* colb, float* dinv,
                      int* rstartP, int* rlenP, float* dinvP, int* nodeid) {
    __shared__ int dh[128], db[128], ch[128], sk[128];
    const int R = 1 << rsh;                // 128
    const int b = blockIdx.x, t = threadIdx.x, nt = blockDim.x;
    const int mask = R - 1;
    for (int r = t; r < R; r += nt) { dh[r] = 0; ch[r] = 0; }
    __syncthreads();
    int cnt = bcnt[b]; if (cnt > cap) cnt = cap;
    const unsigned int* eb = bins + (size_t)b * cap;
    for (int e = t; e < cnt; e += nt)
        atomicAdd(&dh[eb[e] & mask], 1);
    __syncthreads();
    if (t < R) db[t] = dh[t];
    __syncthreads();
    for (int off = 1; off < R; off <<= 1) {
        int add = 0;
        if (t < R && t >= off) add = db[t - off];
        __syncthreads();
        if (t < R) db[t] += add;
        __syncthreads();
    }
    const int v0 = b << rsh;
    const int gbase = b * cap;
    if (t < R) {
        int v = v0 + t;
        if (v < n) dinv[v] = rsqrtf((float)(dh[t] + 1));
        sk[t] = (dh[t] << 7) | t;          // sort key: degree-major
    }
    __syncthreads();
    // bitonic sort of 128 keys (ascending)
    for (int k = 2; k <= R; k <<= 1) {
        for (int jj = k >> 1; jj > 0; jj >>= 1) {
            if (t < R) {
                int ixj = t ^ jj;
                if (ixj > t) {
                    int va = sk[t], vb = sk[ixj];
                    bool up = ((t & k) == 0);
                    bool sw = up ? (va > vb) : (va < vb);
                    if (sw) { sk[t] = vb; sk[ixj] = va; }
                }
            }
            __syncthreads();
        }
    }
    if (t < R) {
        int r = sk[t] & mask;
        int len = sk[t] >> 7;
        int v = v0 + r;
        int gi = v0 + t;
        bool valid = (v < n);
        rstartP[gi] = gbase + db[r] - len;
        rlenP[gi]   = valid ? len : 0;
        dinvP[gi]   = rsqrtf((float)(len + 1));
        nodeid[gi]  = valid ? v : -1;
    }
    __syncthreads();
    for (int e = t; e < cnt; e += nt) {
        unsigned int w = eb[e];
        int r = w & mask;
        int pos = (db[r] - dh[r]) + atomicAdd(&ch[r], 1);
        colb[gbase + pos] = (int)(w >> rsh);
    }
}

// ---------------- consts: M = W1^3 W2 ; cvecs = {g3,g2,g1,b2} ----------------
#define TS 68
__global__ void k_consts(const void* W1, const void* b1, const void* W2, const void* b2,
                         float* M, float* cvecs, const int* flags) {
    __shared__ float A[64 * 64];
    __shared__ float T1[64 * TS];
    __shared__ float T2[64 * TS];
    __shared__ float B2[64 * 16];
    __shared__ float bv[64], bw1[64], bw2[64];
    int bf = flags[0];
    int t = threadIdx.x;   // 256 threads
    for (int i = t; i < 4096; i += 256) A[i] = loadF(W1, i, bf);
    for (int i = t; i < 1024; i += 256) B2[i] = loadF(W2, i, bf);
    if (t < 64) bv[t] = loadF(b1, t, bf);
    __syncthreads();

    const int i0 = (t >> 4) * 4;
    const int j0 = (t & 15) * 4;
    {   // T1 = A @ A
        float acc[4][4] = {};
#pragma unroll 8
        for (int k = 0; k < 64; ++k) {
            float a0 = A[(i0 + 0) * 64 + k];
            float a1 = A[(i0 + 1) * 64 + k];
            float a2 = A[(i0 + 2) * 64 + k];
            float a3 = A[(i0 + 3) * 64 + k];
            float4 bq = *(const float4*)&A[k * 64 + j0];
            acc[0][0] += a0 * bq.x; acc[0][1] += a0 * bq.y; acc[0][2] += a0 * bq.z; acc[0][3] += a0 * bq.w;
            acc[1][0] += a1 * bq.x; acc[1][1] += a1 * bq.y; acc[1][2] += a1 * bq.z; acc[1][3] += a1 * bq.w;
            acc[2][0] += a2 * bq.x; acc[2][1] += a2 * bq.y; acc[2][2] += a2 * bq.z; acc[2][3] += a2 * bq.w;
            acc[3][0] += a3 * bq.x; acc[3][1] += a3 * bq.y; acc[3][2] += a3 * bq.z; acc[3][3] += a3 * bq.w;
        }
#pragma unroll
        for (int ii = 0; ii < 4; ++ii)
            *(float4*)&T1[(i0 + ii) * TS + j0] = make_float4(acc[ii][0], acc[ii][1], acc[ii][2], acc[ii][3]);
    }
    if (t < 64) {
        float acc = 0.f;
#pragma unroll 8
        for (int i = 0; i < 64; ++i) acc += bv[i] * A[i * 64 + t];
        bw1[t] = acc;
    }
    __syncthreads();
    {   // T2 = T1 @ A
        float acc[4][4] = {};
#pragma unroll 8
        for (int k = 0; k < 64; ++k) {
            float a0 = T1[(i0 + 0) * TS + k];
            float a1 = T1[(i0 + 1) * TS + k];
            float a2 = T1[(i0 + 2) * TS + k];
            float a3 = T1[(i0 + 3) * TS + k];
            float4 bq = *(const float4*)&A[k * 64 + j0];
            acc[0][0] += a0 * bq.x; acc[0][1] += a0 * bq.y; acc[0][2] += a0 * bq.z; acc[0][3] += a0 * bq.w;
            acc[1][0] += a1 * bq.x; acc[1][1] += a1 * bq.y; acc[1][2] += a1 * bq.z; acc[1][3] += a1 * bq.w;
            acc[2][0] += a2 * bq.x; acc[2][1] += a2 * bq.y; acc[2][2] += a2 * bq.z; acc[2][3] += a2 * bq.w;
            acc[3][0] += a3 * bq.x; acc[3][1] += a3 * bq.y; acc[3][2] += a3 * bq.z; acc[3][3] += a3 * bq.w;
        }
#pragma unroll
        for (int ii = 0; ii < 4; ++ii)
            *(float4*)&T2[(i0 + ii) * TS + j0] = make_float4(acc[ii][0], acc[ii][1], acc[ii][2], acc[ii][3]);
    }
    if (t < 64) {
        float acc = 0.f;
#pragma unroll 8
        for (int i = 0; i < 64; ++i) acc += bw1[i] * A[i * 64 + t];
        bw2[t] = acc;
    }
    __syncthreads();
    {   // M = T2 @ B2 (64x16)
        int i = t >> 2, j0m = (t & 3) * 4;
        float4 acc = {0.f, 0.f, 0.f, 0.f};
#pragma unroll 8
        for (int k = 0; k < 64; ++k) {
            float a = T2[i * TS + k];
            float4 bq = *(const float4*)&B2[k * 16 + j0m];
            acc.x += a * bq.x; acc.y += a * bq.y; acc.z += a * bq.z; acc.w += a * bq.w;
        }
        *(float4*)&M[i * 16 + j0m] = acc;
    }
    if (t < 16) {
        float a3 = 0.f, a2 = 0.f, a1 = 0.f;
#pragma unroll 8
        for (int i = 0; i < 64; ++i) {
            float w = B2[i * 16 + t];
            a3 += bw2[i] * w;
            a2 += bw1[i] * w;
            a1 += bv[i] * w;
        }
        cvecs[t] = a3;
        cvecs[16 + t] = a2;
        cvecs[32 + t] = a1;
        cvecs[48 + t] = loadF(b2, t, bf);
    }
}

// ---------------- fused: z0 = dinv*(x@M); 4 x pull-prop layers ----------------
__global__ void k_fused(const void* x, const float* M, const float* cvecs,
                        const float* dinv,
                        const int* rstartP, const int* rlenP, const float* dinvP,
                        const int* nodeid, const int* colb,
                        float* z0, float* z1, void* yout,
                        int n, int npad, int ntiles, const int* flags) {
    __shared__ float Ms[64 * 16];
    __shared__ float xs[16 * 64];
    cg::grid_group grid = cg::this_grid();
    const int t = threadIdx.x;   // 256
    const int bf = flags[0];

    // ---- phase 0: z0 = dinv * (x @ M), grid-stride over 16-row tiles ----
    ((float4*)Ms)[t] = ((const float4*)M)[t];
    for (int tile = blockIdx.x; tile < ntiles; tile += gridDim.x) {
        int base = tile * 16;
        __syncthreads();   // protect xs from previous iteration's readers
        if (!bf) {
            int row = base + (t >> 4);
            float4 v = make_float4(0.f, 0.f, 0.f, 0.f);
            if (row < n) v = ((const float4*)x)[base * 16 + t];
            ((float4*)xs)[t] = v;
        } else {
            for (int k = t; k < 1024; k += 256) {
                int r = k >> 6, cc = k & 63;
                int row = base + r;
                xs[k] = (row < n) ? bf2f(((const unsigned short*)x)[row * 64 + cc]) : 0.f;
            }
        }
        __syncthreads();
        int r = t >> 4, c = t & 15;
        int row = base + r;
        if (row < n) {
            float acc = 0.f;
#pragma unroll
            for (int k = 0; k < 64; ++k) acc += xs[r * 64 + k] * Ms[k * 16 + c];
            z0[row * 16 + c] = dinv[row] * acc;
        }
    }
    __threadfence();
    grid.sync();

    // ---- phases 1..4: pull props ----
    const int work = npad * 4;
    const int gstride = gridDim.x * blockDim.x;
#pragma unroll 1
    for (int layer = 0; layer < 4; ++layer) {
        const float* zin = (layer & 1) ? z1 : z0;
        float* zout = (layer & 1) ? z0 : z1;
        const float* cvec = cvecs + layer * 16;
        const int fin = (layer == 3);
        for (int tid = blockIdx.x * blockDim.x + t; tid < work; tid += gstride) {
            int i = tid >> 2, q = tid & 3;
            int v = nodeid[i];
            if (v < 0) continue;
            int beg = rstartP[i], len = rlenP[i];
            float4 acc = *(const float4*)&zin[(size_t)v * 16 + q * 4];   // self-loop
            int j = beg, end = beg + len;
            for (; j + 2 <= end; j += 2) {
                int c0 = colb[j], c1 = colb[j + 1];
                float4 za = *(const float4*)&zin[(size_t)c0 * 16 + q * 4];
                float4 zb = *(const float4*)&zin[(size_t)c1 * 16 + q * 4];
                acc.x += za.x + zb.x; acc.y += za.y + zb.y;
                acc.z += za.z + zb.z; acc.w += za.w + zb.w;
            }
            if (j < end) {
                int c0 = colb[j];
                float4 za = *(const float4*)&zin[(size_t)c0 * 16 + q * 4];
                acc.x += za.x; acc.y += za.y; acc.z += za.z; acc.w += za.w;
            }
            float dv = dinvP[i];
            float a = fin ? dv : dv * dv;
            float b = fin ? 1.0f : dv;
            float4 cv = *(const float4*)&cvec[q * 4];
            float4 val;
            val.x = a * acc.x + b * cv.x;
            val.y = a * acc.y + b * cv.y;
            val.z = a * acc.z + b * cv.z;
            val.w = a * acc.w + b * cv.w;
            int o = v * 16 + q * 4;
            if (fin) {
                if (bf) {
                    ushort4 ov;
                    ov.x = f2bf(val.x); ov.y = f2bf(val.y); ov.z = f2bf(val.z); ov.w = f2bf(val.w);
                    *(ushort4*)&((unsigned short*)yout)[o] = ov;
                } else {
                    *(float4*)&((float*)yout)[o] = val;
                }
            } else {
                *(float4*)&zout[o] = val;
            }
        }
        if (layer < 3) {
            __threadfence();
            grid.sync();
        }
    }
}

// ---------------- launch ----------------
extern "C" void kernel_launch(void* const* d_in, const int* in_sizes, int n_in,
                              void* d_out, int out_size, void* d_ws, size_t ws_size,
                              hipStream_t stream) {
    const void* x  = d_in[0];
    const void* W1 = d_in[1];
    const void* b1 = d_in[2];
    const void* W2 = d_in[3];
    const void* b2 = d_in[4];
    const void* ei = d_in[5];

    int n = in_sizes[0] / 64;       // 100000
    int E = in_sizes[5] / 2;        // 1000000

    const int rsh = 7;
    const int B = (n + (1 << rsh) - 1) >> rsh;       // 782
    int npad = B << rsh;
    const int avg = E / B;
    int cap = avg + avg / 4 + 128;                    // mean + ~12 sigma slack
    cap = (cap + 31) & ~31;
    int ntiles = (n + 15) / 16;

    char* base = (char*)d_ws;
    size_t off = 0;
    auto carve = [&](size_t bytes) -> void* {
        void* r = base + off;
        off = (off + bytes + 255) & ~(size_t)255;
        return r;
    };
    int*          flags   = (int*)carve(8);
    int*          bcnt    = (int*)carve((size_t)B * 4);
    float*        dinv    = (float*)carve((size_t)n * 4);
    unsigned int* bins    = (unsigned int*)carve((size_t)B * cap * 4);
    int*          colb    = (int*)carve((size_t)B * cap * 4);
    int*          rstartP = (int*)carve((size_t)npad * 4);
    int*          rlenP   = (int*)carve((size_t)npad * 4);
    float*        dinvP   = (float*)carve((size_t)npad * 4);
    int*          nodeid  = (int*)carve((size_t)npad * 4);
    float*        Mm      = (float*)carve(1024 * 4);
    float*        cvecs   = (float*)carve(64 * 4);
    float*        z0      = (float*)carve((size_t)n * 16 * 4);
    float*        z1      = (float*)carve((size_t)n * 16 * 4);
    (void)ws_size; (void)n_in; (void)out_size;

    k_init<<<1, 1024, 0, stream>>>(x, ei, flags, bcnt, B);
    k_bin<<<240, 512, (size_t)2 * B * 4, stream>>>(ei, E, rsh, B, cap, bins, bcnt, flags);
    k_csr<<<B, 256, 0, stream>>>(bins, bcnt, cap, rsh, n, colb, dinv,
                                 rstartP, rlenP, dinvP, nodeid);
    k_consts<<<1, 256, 0, stream>>>(W1, b1, W2, b2, Mm, cvecs, flags);

    // cooperative fused kernel: grid sized to co-residency
    int maxb = 8;
    hipOccupancyMaxActiveBlocksPerMultiprocessor(&maxb, (const void*)k_fused, 256, 0);
    hipDeviceProp_t prop;
    int dev = 0;
    hipGetDevice(&dev);
    hipGetDeviceProperties(&prop, dev);
    int maxgrid = maxb * prop.multiProcessorCount;
    int need = (npad * 4 + 255) / 256;                // 1563-ish
    int grid = need < maxgrid ? need : maxgrid;
    if (grid < 1) grid = 1;

    void* args[] = { (void*)&x, (void*)&Mm, (void*)&cvecs, (void*)&dinv,
                     (void*)&rstartP, (void*)&rlenP, (void*)&dinvP,
                     (void*)&nodeid, (void*)&colb,
                     (void*)&z0, (void*)&z1, (void*)&d_out,
                     (void*)&n, (void*)&npad, (void*)&ntiles, (void*)&flags };
    hipLaunchCooperativeKernel((const void*)k_fused, dim3(grid), dim3(256),
                               args, 0, stream);
}

// Round 8
// 127.404 us; speedup vs baseline: 11.3931x; 11.3931x over previous
//
#include <hip/hip_runtime.h>
#include <hip/hip_bf16.h>
#include <stdint.h>

// ---------------- helpers ----------------
__device__ __forceinline__ float bf2f(unsigned short u) {
    unsigned int x = ((unsigned int)u) << 16;
    return __uint_as_float(x);
}
__device__ __forceinline__ unsigned short f2bf(float f) {
    unsigned int x = __float_as_uint(f);
    unsigned int lsb = (x >> 16) & 1u;
    x += 0x7fffu + lsb;           // round-to-nearest-even
    return (unsigned short)(x >> 16);
}
__device__ __forceinline__ float loadF(const void* p, int i, int isbf) {
    return isbf ? bf2f(((const unsigned short*)p)[i]) : ((const float*)p)[i];
}

// ---------------- init: zero bcnt + dtype flags ----------------
// flags[0] = floats bf16(1)/f32(0); flags[1] = edge_index int64(1)/int32(0)
__global__ void k_init(const void* x, const void* eidx, int* flags, int* bcnt, int B) {
    int t = threadIdx.x;   // 1024
    for (int b = t; b < B; b += blockDim.x) bcnt[b] = 0;
    if (t < 64) {
        const unsigned short* u = (const unsigned short*)x;
        float a = fabsf(bf2f(u[2 * t]));
        bool ok = (a == 0.0f) || (a > 1e-30f && a < 1e4f);
        unsigned long long mbf = __ballot(ok);
        if (t == 0) flags[0] = (mbf == ~0ULL) ? 1 : 0;
    } else if (t < 128) {
        int l = t - 64;
        const int* ip = (const int*)eidx;
        unsigned long long mi64 = __ballot(ip[2 * l + 1] == 0);
        if (l == 0) flags[1] = (mi64 == ~0ULL) ? 1 : 0;
    }
}

// ---------------- edge binning by dst range ----------------
// Bucket = dst >> rsh (R=128). Packed word = (src << rsh) | (dst & R-1).
__global__ void k_bin(const void* eidx, int E, int rsh, int B, int cap,
                      unsigned int* bins, int* bcnt, const int* flags) {
    extern __shared__ int sh[];            // 2*B ints
    int* hist   = sh;
    int* base_s = sh + B;
    const int i64 = flags[1];
    const int t = threadIdx.x, nt = blockDim.x;
    const long long i0 = (long long)blockIdx.x * E / gridDim.x;
    const long long i1 = (long long)(blockIdx.x + 1) * E / gridDim.x;
    const long long* e64 = (const long long*)eidx;
    const int* e32 = (const int*)eidx;
    const int mask = (1 << rsh) - 1;

    for (int b = t; b < B; b += nt) hist[b] = 0;
    __syncthreads();
    for (long long i = i0 + t; i < i1; i += nt) {
        int d = i64 ? (int)e64[E + i] : e32[E + i];
        atomicAdd(&hist[d >> rsh], 1);
    }
    __syncthreads();
    for (int b = t; b < B; b += nt) {
        int c = hist[b];
        base_s[b] = c ? atomicAdd(&bcnt[b], c) : 0;
        hist[b] = 0;
    }
    __syncthreads();
    for (long long i = i0 + t; i < i1; i += nt) {
        int d, s;
        if (i64) { d = (int)e64[E + i]; s = (int)e64[i]; }
        else     { d = e32[E + i];     s = e32[i]; }
        int b = d >> rsh;
        int pos = base_s[b] + atomicAdd(&hist[b], 1);
        if (pos >= cap) pos = cap - 1;     // paranoia guard
        bins[(size_t)b * cap + pos] = ((unsigned int)s << rsh) | (unsigned int)(d & mask);
    }
}

// ---------------- per-bucket CSR build: colb + packed meta + dinv ----------------
// meta[v] = { rstart, len, dinv_bits, 0 }
__global__ void k_csr(const unsigned int* bins, const int* bcnt, int cap, int rsh,
                      int n, int* colb, float* dinv, int4* meta) {
    __shared__ int dh[128], db[128], ch[128];
    const int R = 1 << rsh;                // 128
    const int b = blockIdx.x, t = threadIdx.x, nt = blockDim.x;
    const int mask = R - 1;
    for (int r = t; r < R; r += nt) { dh[r] = 0; ch[r] = 0; }
    __syncthreads();
    int cnt = bcnt[b]; if (cnt > cap) cnt = cap;
    const unsigned int* eb = bins + (size_t)b * cap;
    for (int e = t; e < cnt; e += nt)
        atomicAdd(&dh[eb[e] & mask], 1);
    __syncthreads();
    if (t < R) db[t] = dh[t];
    __syncthreads();
    for (int off = 1; off < R; off <<= 1) {
        int add = 0;
        if (t < R && t >= off) add = db[t - off];
        __syncthreads();
        if (t < R) db[t] += add;
        __syncthreads();
    }
    const int v0 = b << rsh;
    const int gbase = b * cap;
    if (t < R) {
        int v = v0 + t;
        if (v < n) {
            int len = dh[t];
            float dv = rsqrtf((float)(len + 1));
            dinv[v] = dv;
            meta[v] = make_int4(gbase + db[t] - len, len, __float_as_int(dv), 0);
        }
    }
    __syncthreads();
    for (int e = t; e < cnt; e += nt) {
        unsigned int w = eb[e];
        int r = w & mask;
        int pos = (db[r] - dh[r]) + atomicAdd(&ch[r], 1);
        colb[gbase + pos] = (int)(w >> rsh);
    }
}

// ---------------- consts: M = W1^3 W2 ; cvecs = {g3,g2,g1,b2} ----------------
#define TS 68
__global__ void k_consts(const void* W1, const void* b1, const void* W2, const void* b2,
                         float* M, float* cvecs, const int* flags) {
    __shared__ float A[64 * 64];
    __shared__ float T1[64 * TS];
    __shared__ float T2[64 * TS];
    __shared__ float B2[64 * 16];
    __shared__ float bv[64], bw1[64], bw2[64];
    int bf = flags[0];
    int t = threadIdx.x;   // 256 threads
    for (int i = t; i < 4096; i += 256) A[i] = loadF(W1, i, bf);
    for (int i = t; i < 1024; i += 256) B2[i] = loadF(W2, i, bf);
    if (t < 64) bv[t] = loadF(b1, t, bf);
    __syncthreads();

    const int i0 = (t >> 4) * 4;
    const int j0 = (t & 15) * 4;
    {   // T1 = A @ A
        float acc[4][4] = {};
#pragma unroll 8
        for (int k = 0; k < 64; ++k) {
            float a0 = A[(i0 + 0) * 64 + k];
            float a1 = A[(i0 + 1) * 64 + k];
            float a2 = A[(i0 + 2) * 64 + k];
            float a3 = A[(i0 + 3) * 64 + k];
            float4 bq = *(const float4*)&A[k * 64 + j0];
            acc[0][0] += a0 * bq.x; acc[0][1] += a0 * bq.y; acc[0][2] += a0 * bq.z; acc[0][3] += a0 * bq.w;
            acc[1][0] += a1 * bq.x; acc[1][1] += a1 * bq.y; acc[1][2] += a1 * bq.z; acc[1][3] += a1 * bq.w;
            acc[2][0] += a2 * bq.x; acc[2][1] += a2 * bq.y; acc[2][2] += a2 * bq.z; acc[2][3] += a2 * bq.w;
            acc[3][0] += a3 * bq.x; acc[3][1] += a3 * bq.y; acc[3][2] += a3 * bq.z; acc[3][3] += a3 * bq.w;
        }
#pragma unroll
        for (int ii = 0; ii < 4; ++ii)
            *(float4*)&T1[(i0 + ii) * TS + j0] = make_float4(acc[ii][0], acc[ii][1], acc[ii][2], acc[ii][3]);
    }
    if (t < 64) {
        float acc = 0.f;
#pragma unroll 8
        for (int i = 0; i < 64; ++i) acc += bv[i] * A[i * 64 + t];
        bw1[t] = acc;
    }
    __syncthreads();
    {   // T2 = T1 @ A
        float acc[4][4] = {};
#pragma unroll 8
        for (int k = 0; k < 64; ++k) {
            float a0 = T1[(i0 + 0) * TS + k];
            float a1 = T1[(i0 + 1) * TS + k];
            float a2 = T1[(i0 + 2) * TS + k];
            float a3 = T1[(i0 + 3) * TS + k];
            float4 bq = *(const float4*)&A[k * 64 + j0];
            acc[0][0] += a0 * bq.x; acc[0][1] += a0 * bq.y; acc[0][2] += a0 * bq.z; acc[0][3] += a0 * bq.w;
            acc[1][0] += a1 * bq.x; acc[1][1] += a1 * bq.y; acc[1][2] += a1 * bq.z; acc[1][3] += a1 * bq.w;
            acc[2][0] += a2 * bq.x; acc[2][1] += a2 * bq.y; acc[2][2] += a2 * bq.z; acc[2][3] += a2 * bq.w;
            acc[3][0] += a3 * bq.x; acc[3][1] += a3 * bq.y; acc[3][2] += a3 * bq.z; acc[3][3] += a3 * bq.w;
        }
#pragma unroll
        for (int ii = 0; ii < 4; ++ii)
            *(float4*)&T2[(i0 + ii) * TS + j0] = make_float4(acc[ii][0], acc[ii][1], acc[ii][2], acc[ii][3]);
    }
    if (t < 64) {
        float acc = 0.f;
#pragma unroll 8
        for (int i = 0; i < 64; ++i) acc += bw1[i] * A[i * 64 + t];
        bw2[t] = acc;
    }
    __syncthreads();
    {   // M = T2 @ B2 (64x16)
        int i = t >> 2, j0m = (t & 3) * 4;
        float4 acc = {0.f, 0.f, 0.f, 0.f};
#pragma unroll 8
        for (int k = 0; k < 64; ++k) {
            float a = T2[i * TS + k];
            float4 bq = *(const float4*)&B2[k * 16 + j0m];
            acc.x += a * bq.x; acc.y += a * bq.y; acc.z += a * bq.z; acc.w += a * bq.w;
        }
        *(float4*)&M[i * 16 + j0m] = acc;
    }
    if (t < 16) {
        float a3 = 0.f, a2 = 0.f, a1 = 0.f;
#pragma unroll 8
        for (int i = 0; i < 64; ++i) {
            float w = B2[i * 16 + t];
            a3 += bw2[i] * w;
            a2 += bw1[i] * w;
            a1 += bv[i] * w;
        }
        cvecs[t] = a3;
        cvecs[16 + t] = a2;
        cvecs[32 + t] = a1;
        cvecs[48 + t] = loadF(b2, t, bf);
    }
}

// ---------------- z0 = dinv * (x @ M) ----------------
__global__ void k_xm(const void* x, const float* M, const float* dinv, float* z0,
                     int n, const int* flags) {
    __shared__ float Ms[64 * 16];
    __shared__ float xs[16 * 64];
    int bf = flags[0];
    int t = threadIdx.x;   // 256
    ((float4*)Ms)[t] = ((const float4*)M)[t];
    int base = blockIdx.x * 16;
    if (!bf) {
        int row = base + (t >> 4);
        float4 v = make_float4(0.f, 0.f, 0.f, 0.f);
        if (row < n) v = ((const float4*)x)[base * 16 + t];
        ((float4*)xs)[t] = v;
    } else {
        for (int k = t; k < 1024; k += 256) {
            int r = k >> 6, cc = k & 63;
            int row = base + r;
            xs[k] = (row < n) ? bf2f(((const unsigned short*)x)[row * 64 + cc]) : 0.f;
        }
    }
    __syncthreads();
    int r = t >> 4, c = t & 15;
    int row = base + r;
    if (row < n) {
        float acc = 0.f;
#pragma unroll
        for (int k = 0; k < 64; ++k) acc += xs[r * 64 + k] * Ms[k * 16 + c];
        z0[row * 16 + c] = dinv[row] * acc;   // z-space
    }
}

// ---------------- pull propagation: packed meta, 4-way unroll, 4 lanes/node ---
// sum = z[v] + sum_{s in N(v)} z[s]
// non-final: zout = dinv^2*sum + dinv*cvec ; final: yout = dinv*sum + cvec
__global__ void k_prop(const float* zin, void* yout, const int4* meta,
                       const int* colb, const float* cvec,
                       int n, int is_final, const int* flags) {
    int tid = blockIdx.x * blockDim.x + threadIdx.x;
    int v = tid >> 2, q = tid & 3;
    if (v >= n) return;
    int4 m = meta[v];                      // {rstart, len, dinv_bits, 0}
    int beg = m.x, len = m.y;
    float4 acc = *(const float4*)&zin[(size_t)v * 16 + q * 4];   // self-loop
    int j = beg, end = beg + len;
    for (; j + 4 <= end; j += 4) {         // 4 gathers in flight
        int c0 = colb[j], c1 = colb[j + 1], c2 = colb[j + 2], c3 = colb[j + 3];
        float4 za = *(const float4*)&zin[(size_t)c0 * 16 + q * 4];
        float4 zb = *(const float4*)&zin[(size_t)c1 * 16 + q * 4];
        float4 zc = *(const float4*)&zin[(size_t)c2 * 16 + q * 4];
        float4 zd = *(const float4*)&zin[(size_t)c3 * 16 + q * 4];
        acc.x += (za.x + zb.x) + (zc.x + zd.x);
        acc.y += (za.y + zb.y) + (zc.y + zd.y);
        acc.z += (za.z + zb.z) + (zc.z + zd.z);
        acc.w += (za.w + zb.w) + (zc.w + zd.w);
    }
    for (; j < end; ++j) {
        int c0 = colb[j];
        float4 za = *(const float4*)&zin[(size_t)c0 * 16 + q * 4];
        acc.x += za.x; acc.y += za.y; acc.z += za.z; acc.w += za.w;
    }
    float dv = __int_as_float(m.z);
    float a = is_final ? dv : dv * dv;
    float b = is_final ? 1.0f : dv;
    float4 cv = *(const float4*)&cvec[q * 4];
    float4 val;
    val.x = a * acc.x + b * cv.x;
    val.y = a * acc.y + b * cv.y;
    val.z = a * acc.z + b * cv.z;
    val.w = a * acc.w + b * cv.w;
    int o = v * 16 + q * 4;
    if (is_final && flags[0]) {
        ushort4 ov;
        ov.x = f2bf(val.x); ov.y = f2bf(val.y); ov.z = f2bf(val.z); ov.w = f2bf(val.w);
        *(ushort4*)&((unsigned short*)yout)[o] = ov;
    } else {
        *(float4*)&((float*)yout)[o] = val;
    }
}

// ---------------- launch ----------------
extern "C" void kernel_launch(void* const* d_in, const int* in_sizes, int n_in,
                              void* d_out, int out_size, void* d_ws, size_t ws_size,
                              hipStream_t stream) {
    const void* x  = d_in[0];
    const void* W1 = d_in[1];
    const void* b1 = d_in[2];
    const void* W2 = d_in[3];
    const void* b2 = d_in[4];
    const void* ei = d_in[5];

    const int n = in_sizes[0] / 64;       // 100000
    const int E = in_sizes[5] / 2;        // 1000000

    const int rsh = 7;
    const int B = (n + (1 << rsh) - 1) >> rsh;       // 782
    const int avg = E / B;
    int cap = avg + avg / 4 + 128;                    // mean + ~12 sigma slack
    cap = (cap + 31) & ~31;

    char* base = (char*)d_ws;
    size_t off = 0;
    auto carve = [&](size_t bytes) -> void* {
        void* r = base + off;
        off = (off + bytes + 255) & ~(size_t)255;
        return r;
    };
    int*          flags  = (int*)carve(8);
    int*          bcnt   = (int*)carve((size_t)B * 4);
    float*        dinv   = (float*)carve((size_t)n * 4);
    unsigned int* bins   = (unsigned int*)carve((size_t)B * cap * 4);
    int*          colb   = (int*)carve((size_t)B * cap * 4);
    int4*         meta   = (int4*)carve((size_t)n * 16);
    float*        Mm     = (float*)carve(1024 * 4);
    float*        cvecs  = (float*)carve(64 * 4);
    float*        z0     = (float*)carve((size_t)n * 16 * 4);
    float*        z1     = (float*)carve((size_t)n * 16 * 4);
    (void)ws_size; (void)n_in; (void)out_size;

    k_init<<<1, 1024, 0, stream>>>(x, ei, flags, bcnt, B);
    k_bin<<<240, 512, (size_t)2 * B * 4, stream>>>(ei, E, rsh, B, cap, bins, bcnt, flags);
    k_csr<<<B, 256, 0, stream>>>(bins, bcnt, cap, rsh, n, colb, dinv, meta);
    k_consts<<<1, 256, 0, stream>>>(W1, b1, W2, b2, Mm, cvecs, flags);
    k_xm<<<(n + 15) / 16, 256, 0, stream>>>(x, Mm, dinv, z0, n, flags);

    const int pgrid = (n * 4 + 255) / 256;
    k_prop<<<pgrid, 256, 0, stream>>>(z0, z1, meta, colb, cvecs + 0,  n, 0, flags);
    k_prop<<<pgrid, 256, 0, stream>>>(z1, z0, meta, colb, cvecs + 16, n, 0, flags);
    k_prop<<<pgrid, 256, 0, stream>>>(z0, z1, meta, colb, cvecs + 32, n, 0, flags);
    k_prop<<<pgrid, 256, 0, stream>>>(z1, d_out, meta, colb, cvecs + 48, n, 1, flags);
}

// Round 9
// 100.465 us; speedup vs baseline: 14.4480x; 1.2681x over previous
//
#include <hip/hip_runtime.h>
#include <hip/hip_bf16.h>
#include <stdint.h>

// ---------------- helpers ----------------
__device__ __forceinline__ float bf2f(unsigned short u) {
    unsigned int x = ((unsigned int)u) << 16;
    return __uint_as_float(x);
}
__device__ __forceinline__ unsigned short f2bf(float f) {
    unsigned int x = __float_as_uint(f);
    unsigned int lsb = (x >> 16) & 1u;
    x += 0x7fffu + lsb;           // round-to-nearest-even
    return (unsigned short)(x >> 16);
}
__device__ __forceinline__ float loadF(const void* p, int i, int isbf) {
    return isbf ? bf2f(((const unsigned short*)p)[i]) : ((const float*)p)[i];
}

// ---------------- init: zero bcnt + dtype flags ----------------
// flags[0] = floats bf16(1)/f32(0); flags[1] = edge_index int64(1)/int32(0)
__global__ void k_init(const void* x, const void* eidx, int* flags, int* bcnt, int B) {
    int t = threadIdx.x;   // 1024
    for (int b = t; b < B; b += blockDim.x) bcnt[b] = 0;
    if (t < 64) {
        const unsigned short* u = (const unsigned short*)x;
        float a = fabsf(bf2f(u[2 * t]));
        bool ok = (a == 0.0f) || (a > 1e-30f && a < 1e4f);
        unsigned long long mbf = __ballot(ok);
        if (t == 0) flags[0] = (mbf == ~0ULL) ? 1 : 0;
    } else if (t < 128) {
        int l = t - 64;
        const int* ip = (const int*)eidx;
        unsigned long long mi64 = __ballot(ip[2 * l + 1] == 0);
        if (l == 0) flags[1] = (mi64 == ~0ULL) ? 1 : 0;
    }
}

// ---------------- fused: edge binning (blocks 0..G-1) + consts (block G) -------
// Binning: bucket = dst >> rsh (R=128). Packed word = (src << rsh) | (dst & R-1).
// Consts: M = W1^3 W2 ; cvecs = {g3=b1W1^2W2, g2=b1W1W2, g1=b1W2, b2}
#define TS 68
__global__ void k_bin(const void* eidx, int E, int rsh, int B, int cap,
                      unsigned int* bins, int* bcnt, const int* flags,
                      const void* W1, const void* b1, const void* W2, const void* b2,
                      float* M, float* cvecs, int nbin) {
    // ---- consts block ----
    if ((int)blockIdx.x == nbin) {
        __shared__ float A[64 * 64];
        __shared__ float T1[64 * TS];
        __shared__ float T2[64 * TS];
        __shared__ float B2s[64 * 16];
        __shared__ float bv[64], bw1[64], bw2[64];
        int bf = flags[0];
        int t = threadIdx.x;   // 512 threads; use 256
        if (t < 256) {
            for (int i = t; i < 4096; i += 256) A[i] = loadF(W1, i, bf);
            for (int i = t; i < 1024; i += 256) B2s[i] = loadF(W2, i, bf);
            if (t < 64) bv[t] = loadF(b1, t, bf);
        }
        __syncthreads();
        if (t < 256) {
            const int i0 = (t >> 4) * 4;
            const int j0 = (t & 15) * 4;
            {   // T1 = A @ A
                float acc[4][4] = {};
#pragma unroll 8
                for (int k = 0; k < 64; ++k) {
                    float a0 = A[(i0 + 0) * 64 + k];
                    float a1 = A[(i0 + 1) * 64 + k];
                    float a2 = A[(i0 + 2) * 64 + k];
                    float a3 = A[(i0 + 3) * 64 + k];
                    float4 bq = *(const float4*)&A[k * 64 + j0];
                    acc[0][0] += a0 * bq.x; acc[0][1] += a0 * bq.y; acc[0][2] += a0 * bq.z; acc[0][3] += a0 * bq.w;
                    acc[1][0] += a1 * bq.x; acc[1][1] += a1 * bq.y; acc[1][2] += a1 * bq.z; acc[1][3] += a1 * bq.w;
                    acc[2][0] += a2 * bq.x; acc[2][1] += a2 * bq.y; acc[2][2] += a2 * bq.z; acc[2][3] += a2 * bq.w;
                    acc[3][0] += a3 * bq.x; acc[3][1] += a3 * bq.y; acc[3][2] += a3 * bq.z; acc[3][3] += a3 * bq.w;
                }
#pragma unroll
                for (int ii = 0; ii < 4; ++ii)
                    *(float4*)&T1[(i0 + ii) * TS + j0] = make_float4(acc[ii][0], acc[ii][1], acc[ii][2], acc[ii][3]);
            }
            if (t < 64) {
                float acc = 0.f;
#pragma unroll 8
                for (int i = 0; i < 64; ++i) acc += bv[i] * A[i * 64 + t];
                bw1[t] = acc;
            }
        }
        __syncthreads();
        if (t < 256) {
            const int i0 = (t >> 4) * 4;
            const int j0 = (t & 15) * 4;
            {   // T2 = T1 @ A
                float acc[4][4] = {};
#pragma unroll 8
                for (int k = 0; k < 64; ++k) {
                    float a0 = T1[(i0 + 0) * TS + k];
                    float a1 = T1[(i0 + 1) * TS + k];
                    float a2 = T1[(i0 + 2) * TS + k];
                    float a3 = T1[(i0 + 3) * TS + k];
                    float4 bq = *(const float4*)&A[k * 64 + j0];
                    acc[0][0] += a0 * bq.x; acc[0][1] += a0 * bq.y; acc[0][2] += a0 * bq.z; acc[0][3] += a0 * bq.w;
                    acc[1][0] += a1 * bq.x; acc[1][1] += a1 * bq.y; acc[1][2] += a1 * bq.z; acc[1][3] += a1 * bq.w;
                    acc[2][0] += a2 * bq.x; acc[2][1] += a2 * bq.y; acc[2][2] += a2 * bq.z; acc[2][3] += a2 * bq.w;
                    acc[3][0] += a3 * bq.x; acc[3][1] += a3 * bq.y; acc[3][2] += a3 * bq.z; acc[3][3] += a3 * bq.w;
                }
#pragma unroll
                for (int ii = 0; ii < 4; ++ii)
                    *(float4*)&T2[(i0 + ii) * TS + j0] = make_float4(acc[ii][0], acc[ii][1], acc[ii][2], acc[ii][3]);
            }
            if (t < 64) {
                float acc = 0.f;
#pragma unroll 8
                for (int i = 0; i < 64; ++i) acc += bw1[i] * A[i * 64 + t];
                bw2[t] = acc;
            }
        }
        __syncthreads();
        if (t < 256) {
            {   // M = T2 @ B2 (64x16)
                int i = t >> 2, j0m = (t & 3) * 4;
                float4 acc = {0.f, 0.f, 0.f, 0.f};
#pragma unroll 8
                for (int k = 0; k < 64; ++k) {
                    float a = T2[i * TS + k];
                    float4 bq = *(const float4*)&B2s[k * 16 + j0m];
                    acc.x += a * bq.x; acc.y += a * bq.y; acc.z += a * bq.z; acc.w += a * bq.w;
                }
                *(float4*)&M[i * 16 + j0m] = acc;
            }
            if (t < 16) {
                float a3 = 0.f, a2 = 0.f, a1 = 0.f;
#pragma unroll 8
                for (int i = 0; i < 64; ++i) {
                    float w = B2s[i * 16 + t];
                    a3 += bw2[i] * w;
                    a2 += bw1[i] * w;
                    a1 += bv[i] * w;
                }
                cvecs[t] = a3;
                cvecs[16 + t] = a2;
                cvecs[32 + t] = a1;
                cvecs[48 + t] = loadF(b2, t, flags[0]);
            }
        }
        return;
    }
    // ---- binning blocks ----
    extern __shared__ int sh[];            // 2*B ints
    int* hist   = sh;
    int* base_s = sh + B;
    const int i64 = flags[1];
    const int t = threadIdx.x, nt = blockDim.x;
    const long long i0 = (long long)blockIdx.x * E / nbin;
    const long long i1 = (long long)(blockIdx.x + 1) * E / nbin;
    const long long* e64 = (const long long*)eidx;
    const int* e32 = (const int*)eidx;
    const int mask = (1 << rsh) - 1;

    for (int b = t; b < B; b += nt) hist[b] = 0;
    __syncthreads();
    for (long long i = i0 + t; i < i1; i += nt) {
        int d = i64 ? (int)e64[E + i] : e32[E + i];
        atomicAdd(&hist[d >> rsh], 1);
    }
    __syncthreads();
    for (int b = t; b < B; b += nt) {
        int c = hist[b];
        base_s[b] = c ? atomicAdd(&bcnt[b], c) : 0;
        hist[b] = 0;
    }
    __syncthreads();
    for (long long i = i0 + t; i < i1; i += nt) {
        int d, s;
        if (i64) { d = (int)e64[E + i]; s = (int)e64[i]; }
        else     { d = e32[E + i];     s = e32[i]; }
        int b = d >> rsh;
        int pos = base_s[b] + atomicAdd(&hist[b], 1);
        if (pos >= cap) pos = cap - 1;     // paranoia guard
        bins[(size_t)b * cap + pos] = ((unsigned int)s << rsh) | (unsigned int)(d & mask);
    }
}

// ---------------- per-bucket CSR build: colb + packed meta ----------------
// meta[v] = { rstart, len, dinv_bits, 0 }
__global__ void k_csr(const unsigned int* bins, const int* bcnt, int cap, int rsh,
                      int n, int* colb, int4* meta) {
    __shared__ int dh[128], db[128], ch[128];
    const int R = 1 << rsh;                // 128
    const int b = blockIdx.x, t = threadIdx.x, nt = blockDim.x;
    const int mask = R - 1;
    for (int r = t; r < R; r += nt) { dh[r] = 0; ch[r] = 0; }
    __syncthreads();
    int cnt = bcnt[b]; if (cnt > cap) cnt = cap;
    const unsigned int* eb = bins + (size_t)b * cap;
    for (int e = t; e < cnt; e += nt)
        atomicAdd(&dh[eb[e] & mask], 1);
    __syncthreads();
    if (t < R) db[t] = dh[t];
    __syncthreads();
    for (int off = 1; off < R; off <<= 1) {
        int add = 0;
        if (t < R && t >= off) add = db[t - off];
        __syncthreads();
        if (t < R) db[t] += add;
        __syncthreads();
    }
    const int v0 = b << rsh;
    const int gbase = b * cap;
    if (t < R) {
        int v = v0 + t;
        if (v < n) {
            int len = dh[t];
            float dv = rsqrtf((float)(len + 1));
            meta[v] = make_int4(gbase + db[t] - len, len, __float_as_int(dv), 0);
        }
    }
    __syncthreads();
    for (int e = t; e < cnt; e += nt) {
        unsigned int w = eb[e];
        int r = w & mask;
        int pos = (db[r] - dh[r]) + atomicAdd(&ch[r], 1);
        colb[gbase + pos] = (int)(w >> rsh);
    }
}

// ---------------- z0 = bf16( dinv * (x @ M) ) ----------------
__global__ void k_xm(const void* x, const float* M, const int4* meta,
                     unsigned short* z0, int n, const int* flags) {
    __shared__ float Ms[64 * 16];
    __shared__ float xs[16 * 64];
    int bf = flags[0];
    int t = threadIdx.x;   // 256
    ((float4*)Ms)[t] = ((const float4*)M)[t];
    int base = blockIdx.x * 16;
    if (!bf) {
        int row = base + (t >> 4);
        float4 v = make_float4(0.f, 0.f, 0.f, 0.f);
        if (row < n) v = ((const float4*)x)[base * 16 + t];
        ((float4*)xs)[t] = v;
    } else {
        for (int k = t; k < 1024; k += 256) {
            int r = k >> 6, cc = k & 63;
            int row = base + r;
            xs[k] = (row < n) ? bf2f(((const unsigned short*)x)[row * 64 + cc]) : 0.f;
        }
    }
    __syncthreads();
    int r = t >> 4, c = t & 15;
    int row = base + r;
    if (row < n) {
        float acc = 0.f;
#pragma unroll
        for (int k = 0; k < 64; ++k) acc += xs[r * 64 + k] * Ms[k * 16 + c];
        float dv = __int_as_float(meta[row].z);
        z0[row * 16 + c] = f2bf(dv * acc);   // bf16 z-space
    }
}

// ---------------- pull propagation: bf16 z, packed meta, 4 lanes/node ---------
// sum = z[v] + sum_{s in N(v)} z[s]
// non-final: zout = bf16(dinv^2*sum + dinv*cvec) ; final: yout = dinv*sum + cvec
__global__ void k_prop(const unsigned short* zin, void* yout, const int4* meta,
                       const int* colb, const float* cvec,
                       int n, int is_final, const int* flags) {
    int tid = blockIdx.x * blockDim.x + threadIdx.x;
    int v = tid >> 2, q = tid & 3;
    if (v >= n) return;
    int4 m = meta[v];                      // {rstart, len, dinv_bits, 0}
    int beg = m.x, len = m.y;
    ushort4 sv = *(const ushort4*)&zin[(size_t)v * 16 + q * 4];   // self-loop
    float4 acc = make_float4(bf2f(sv.x), bf2f(sv.y), bf2f(sv.z), bf2f(sv.w));
    int j = beg, end = beg + len;
    for (; j + 4 <= end; j += 4) {         // 4 gathers in flight
        int c0 = colb[j], c1 = colb[j + 1], c2 = colb[j + 2], c3 = colb[j + 3];
        ushort4 za = *(const ushort4*)&zin[(size_t)c0 * 16 + q * 4];
        ushort4 zb = *(const ushort4*)&zin[(size_t)c1 * 16 + q * 4];
        ushort4 zc = *(const ushort4*)&zin[(size_t)c2 * 16 + q * 4];
        ushort4 zd = *(const ushort4*)&zin[(size_t)c3 * 16 + q * 4];
        acc.x += (bf2f(za.x) + bf2f(zb.x)) + (bf2f(zc.x) + bf2f(zd.x));
        acc.y += (bf2f(za.y) + bf2f(zb.y)) + (bf2f(zc.y) + bf2f(zd.y));
        acc.z += (bf2f(za.z) + bf2f(zb.z)) + (bf2f(zc.z) + bf2f(zd.z));
        acc.w += (bf2f(za.w) + bf2f(zb.w)) + (bf2f(zc.w) + bf2f(zd.w));
    }
    for (; j < end; ++j) {
        int c0 = colb[j];
        ushort4 za = *(const ushort4*)&zin[(size_t)c0 * 16 + q * 4];
        acc.x += bf2f(za.x); acc.y += bf2f(za.y); acc.z += bf2f(za.z); acc.w += bf2f(za.w);
    }
    float dv = __int_as_float(m.z);
    float a = is_final ? dv : dv * dv;
    float b = is_final ? 1.0f : dv;
    float4 cv = *(const float4*)&cvec[q * 4];
    float4 val;
    val.x = a * acc.x + b * cv.x;
    val.y = a * acc.y + b * cv.y;
    val.z = a * acc.z + b * cv.z;
    val.w = a * acc.w + b * cv.w;
    int o = v * 16 + q * 4;
    if (is_final) {
        if (flags[0]) {
            ushort4 ov;
            ov.x = f2bf(val.x); ov.y = f2bf(val.y); ov.z = f2bf(val.z); ov.w = f2bf(val.w);
            *(ushort4*)&((unsigned short*)yout)[o] = ov;
        } else {
            *(float4*)&((float*)yout)[o] = val;
        }
    } else {
        ushort4 ov;
        ov.x = f2bf(val.x); ov.y = f2bf(val.y); ov.z = f2bf(val.z); ov.w = f2bf(val.w);
        *(ushort4*)&((unsigned short*)yout)[o] = ov;
    }
}

// ---------------- launch ----------------
extern "C" void kernel_launch(void* const* d_in, const int* in_sizes, int n_in,
                              void* d_out, int out_size, void* d_ws, size_t ws_size,
                              hipStream_t stream) {
    const void* x  = d_in[0];
    const void* W1 = d_in[1];
    const void* b1 = d_in[2];
    const void* W2 = d_in[3];
    const void* b2 = d_in[4];
    const void* ei = d_in[5];

    const int n = in_sizes[0] / 64;       // 100000
    const int E = in_sizes[5] / 2;        // 1000000

    const int rsh = 7;
    const int B = (n + (1 << rsh) - 1) >> rsh;       // 782
    const int avg = E / B;
    int cap = avg + avg / 4 + 128;                    // mean + ~12 sigma slack
    cap = (cap + 31) & ~31;

    char* base = (char*)d_ws;
    size_t off = 0;
    auto carve = [&](size_t bytes) -> void* {
        void* r = base + off;
        off = (off + bytes + 255) & ~(size_t)255;
        return r;
    };
    int*            flags  = (int*)carve(8);
    int*            bcnt   = (int*)carve((size_t)B * 4);
    unsigned int*   bins   = (unsigned int*)carve((size_t)B * cap * 4);
    int*            colb   = (int*)carve((size_t)B * cap * 4);
    int4*           meta   = (int4*)carve((size_t)n * 16);
    float*          Mm     = (float*)carve(1024 * 4);
    float*          cvecs  = (float*)carve(64 * 4);
    unsigned short* z0     = (unsigned short*)carve((size_t)n * 16 * 2);
    unsigned short* z1     = (unsigned short*)carve((size_t)n * 16 * 2);
    (void)ws_size; (void)n_in; (void)out_size;

    const int nbin = 240;
    k_init<<<1, 1024, 0, stream>>>(x, ei, flags, bcnt, B);
    // blocks 0..nbin-1: binning; block nbin: consts (hidden under binning)
    k_bin<<<nbin + 1, 512, (size_t)2 * B * 4, stream>>>(ei, E, rsh, B, cap, bins, bcnt,
                                                        flags, W1, b1, W2, b2, Mm, cvecs, nbin);
    k_csr<<<B, 256, 0, stream>>>(bins, bcnt, cap, rsh, n, colb, meta);
    k_xm<<<(n + 15) / 16, 256, 0, stream>>>(x, Mm, meta, z0, n, flags);

    const int pgrid = (n * 4 + 255) / 256;
    k_prop<<<pgrid, 256, 0, stream>>>(z0, z1, meta, colb, cvecs + 0,  n, 0, flags);
    k_prop<<<pgrid, 256, 0, stream>>>(z1, z0, meta, colb, cvecs + 16, n, 0, flags);
    k_prop<<<pgrid, 256, 0, stream>>>(z0, z1, meta, colb, cvecs + 32, n, 0, flags);
    k_prop<<<pgrid, 256, 0, stream>>>(z1, d_out, meta, colb, cvecs + 48, n, 1, flags);
}